// Round 12
// baseline (266.016 us; speedup 1.0000x reference)
//
#include <hip/hip_runtime.h>
#include <math.h>

#define NT 256

typedef short bf16x8 __attribute__((ext_vector_type(8)));
typedef float f32x4 __attribute__((ext_vector_type(4)));

// IEEE-div silu — R3/R9/R11-proven. Do NOT replace with rcp/NR (fails replay check).
__device__ __forceinline__ float silu_f(float z) {
    return z / (1.0f + __expf(-z));
}
__device__ __forceinline__ unsigned short f2bf(float f) {
    unsigned int u = __float_as_uint(f);
    u += 0x7FFFu + ((u >> 16) & 1u);          // round-to-nearest-even
    return (unsigned short)(u >> 16);
}
__device__ __forceinline__ float bf2f(unsigned short s) {
    return __uint_as_float(((unsigned int)s) << 16);
}
__device__ __forceinline__ unsigned int pk2(unsigned short a, unsigned short b) {
    return (unsigned int)a | ((unsigned int)b << 16);
}

__global__ __launch_bounds__(NT, 2) void backflow_kernel(
    const float* __restrict__ x,
    const float* __restrict__ phi_w1, const float* __restrict__ phi_b1,
    const float* __restrict__ phi_w2, const float* __restrict__ phi_b2,
    const float* __restrict__ psi_w1, const float* __restrict__ psi_b1,
    const float* __restrict__ psi_w2, const float* __restrict__ psi_b2,
    const float* __restrict__ psi_w3, const float* __restrict__ psi_b3,
    const float* __restrict__ bf_scale,
    float* __restrict__ out)
{
    // A = H (64 j x 128 n) bf16 hi/lo, XOR-swizzled rows (proven layout).
    __shared__ __align__(16) unsigned short A_hi[64 * 128];
    __shared__ __align__(16) unsigned short A_lo[64 * 128];
    // F rows for layer-1 MFMA, 80B pitch (64B data + 16B pad -> 2-way-free banks).
    // featA1: [Fhi(0..10),1.0@11 | Fmid(16..26)] ; featA2: [Flo(0..10) | 0]
    __shared__ __align__(16) unsigned char featA1[64 * 80];
    __shared__ __align__(16) unsigned char featA2[64 * 80];
    __shared__ __align__(16) float x_l4[64 * 4];
    __shared__ __align__(16) float upd_l[8 * 132];
    __shared__ float red_l[48];

    const int tid  = threadIdx.x;
    const int b    = blockIdx.x >> 3;
    const int i0   = (blockIdx.x & 7) * 8;
    const int wv   = tid >> 6;          // wave 0..3
    const int lane = tid & 63;
    const int lr   = lane & 15;
    const int lg   = lane >> 4;

    // ---- W2 fragments (hi/lo bf16), register resident; wave owns c-tiles {wv, wv+4} ----
    bf16x8 bh[2][4], bl[2][4];
    float b2c[2];
    #pragma unroll
    for (int c2 = 0; c2 < 2; ++c2) {
        const int ct = wv + 4 * c2;
        const int n  = ct * 16 + lr;
        b2c[c2] = phi_b2[n];
        #pragma unroll
        for (int ks = 0; ks < 4; ++ks) {
            #pragma unroll
            for (int e = 0; e < 8; ++e) {
                const int k = ks * 32 + lg * 8 + e;
                const float w = phi_w2[k * 128 + n];
                const unsigned short h = f2bf(w);
                bh[c2][ks][e] = (short)h;
                bl[c2][ks][e] = (short)f2bf(w - bf2f(h));
            }
        }
    }

    // ---- W1 A-operand variants (exact 3-term split, bias folded via slot 11) ----
    // A-row (l&15) = output channel n. Slot k: d=k&15; d<=10 -> W1[d][n];
    // d==11 in low half -> b1[n]; else 0.  Variants: hi / mid / lo in both halves.
    bf16x8 w1a[2], w1b[2], w1c[2];
    #pragma unroll
    for (int c2 = 0; c2 < 2; ++c2) {
        const int n = (wv + 4 * c2) * 16 + lr;
        #pragma unroll
        for (int e = 0; e < 8; ++e) {
            const int k = lg * 8 + e;
            const int d = k & 15;
            float w = 0.0f;
            if (d <= 10) w = phi_w1[d * 128 + n];
            else if (d == 11 && k < 16) w = phi_b1[n];
            const unsigned short hi = f2bf(w);
            const float rm = w - bf2f(hi);
            const unsigned short md = f2bf(rm);
            const unsigned short lo = f2bf(rm - bf2f(md));
            w1a[c2][e] = (short)hi;
            w1b[c2][e] = (short)md;
            w1c[c2][e] = (short)lo;
        }
    }

    // ---- stage x ----
    if (tid < 64) {
        x_l4[tid * 4 + 0] = x[b * 192 + tid * 3 + 0];
        x_l4[tid * 4 + 1] = x[b * 192 + tid * 3 + 1];
        x_l4[tid * 4 + 2] = x[b * 192 + tid * 3 + 2];
        x_l4[tid * 4 + 3] = 0.0f;
    }
    __syncthreads();

    #pragma unroll 1
    for (int il = 0; il < 8; ++il) {
        const int i = i0 + il;

        // ---- features for this i: lane j builds its packed 3-split rows ----
        if (tid < 64) {
            const int j = tid;
            const float xi0 = x_l4[i * 4 + 0], xi1 = x_l4[i * 4 + 1], xi2 = x_l4[i * 4 + 2];
            const float4 xj4 = *(const float4*)&x_l4[j * 4];
            float F[12];
            F[0] = xi0; F[1] = xi1; F[2] = xi2;
            F[3] = xj4.x; F[4] = xj4.y; F[5] = xj4.z;
            F[6] = xi0 - xj4.x; F[7] = xi1 - xj4.y; F[8] = xi2 - xj4.z;
            const float r2s = F[6] * F[6] + F[7] * F[7] + F[8] * F[8];
            F[9]  = sqrtf(r2s + 1e-12f);
            F[10] = r2s;
            F[11] = 1.0f;                         // bias carrier
            unsigned short fh[12], fm[12], fl[12];
            #pragma unroll
            for (int d = 0; d < 12; ++d) {
                fh[d] = f2bf(F[d]);
                const float rm = F[d] - bf2f(fh[d]);
                fm[d] = f2bf(rm);
                fl[d] = f2bf(rm - bf2f(fm[d]));
            }
            uint4* p1 = (uint4*)(featA1 + j * 80);
            p1[0] = make_uint4(pk2(fh[0], fh[1]), pk2(fh[2], fh[3]), pk2(fh[4], fh[5]), pk2(fh[6], fh[7]));
            p1[1] = make_uint4(pk2(fh[8], fh[9]), pk2(fh[10], fh[11]), 0u, 0u);
            p1[2] = make_uint4(pk2(fm[0], fm[1]), pk2(fm[2], fm[3]), pk2(fm[4], fm[5]), pk2(fm[6], fm[7]));
            p1[3] = make_uint4(pk2(fm[8], fm[9]), pk2(fm[10], 0), 0u, 0u);   // slot27=0 (bias once)
            uint4* p2 = (uint4*)(featA2 + j * 80);
            p2[0] = make_uint4(pk2(fl[0], fl[1]), pk2(fl[2], fl[3]), pk2(fl[4], fl[5]), pk2(fl[6], fl[7]));
            p2[1] = make_uint4(pk2(fl[8], fl[9]), pk2(fl[10], 0), 0u, 0u);   // slot11 lo-bias=fl[11]? no: bias lo via W-side; F2[11]=0
            p2[2] = make_uint4(0u, 0u, 0u, 0u);
            p2[3] = make_uint4(0u, 0u, 0u, 0u);
        }
        __syncthreads();   // barF: featL ready; also fences prev-il layer-2 A reads

        if (tid < 3) upd_l[il * 132 + tid] = x_l4[i * 4 + tid];

        // ---- layer-1 via MFMA: D[n][j] = W1*F exact (hh,hm,mh,mm,lh,hl terms) ----
        #pragma unroll
        for (int jt = 0; jt < 4; ++jt) {
            const int j = jt * 16 + lr;
            const bf16x8 bf1 = *(const bf16x8*)(featA1 + j * 80 + lg * 16);
            const bf16x8 bf2v = *(const bf16x8*)(featA2 + j * 80 + lg * 16);
            #pragma unroll
            for (int c2 = 0; c2 < 2; ++c2) {
                f32x4 acc = {0.0f, 0.0f, 0.0f, 0.0f};
                acc = __builtin_amdgcn_mfma_f32_16x16x32_bf16(w1a[c2], bf1, acc, 0, 0, 0);
                acc = __builtin_amdgcn_mfma_f32_16x16x32_bf16(w1b[c2], bf1, acc, 0, 0, 0);
                acc = __builtin_amdgcn_mfma_f32_16x16x32_bf16(w1c[c2], bf1, acc, 0, 0, 0);
                acc = __builtin_amdgcn_mfma_f32_16x16x32_bf16(w1a[c2], bf2v, acc, 0, 0, 0);
                unsigned short hh[4], ll[4];
                #pragma unroll
                for (int v = 0; v < 4; ++v) {
                    const float h = silu_f(acc[v]);           // bias already inside
                    hh[v] = f2bf(h);
                    ll[v] = f2bf(h - bf2f(hh[v]));
                }
                const int n0 = (wv + 4 * c2) * 16 + lg * 4;
                const int byteoff = ((j * 128 + n0) * 2) ^ ((j & 7) << 4);
                *(ushort4*)((char*)A_hi + byteoff) = make_ushort4(hh[0], hh[1], hh[2], hh[3]);
                *(ushort4*)((char*)A_lo + byteoff) = make_ushort4(ll[0], ll[1], ll[2], ll[3]);
            }
        }
        __syncthreads();   // barA: A ready

        // ---- layer-2 GEMM (MFMA, 3-term bf16 split) + silu + masked j-sum (verbatim R11) ----
        float msum0 = 0.0f, msum1 = 0.0f;
        const int a_base = lr * 256 + lg * 16;
        const int a_swz  = (lr & 7) << 4;
        #pragma unroll
        for (int jt = 0; jt < 4; ++jt) {
            bf16x8 ah[4], al[4];
            #pragma unroll
            for (int ks = 0; ks < 4; ++ks) {
                const int off = (jt * 4096 + ks * 64 + a_base) ^ a_swz;
                ah[ks] = *(const bf16x8*)((const char*)A_hi + off);
                al[ks] = *(const bf16x8*)((const char*)A_lo + off);
            }
            #pragma unroll
            for (int c2 = 0; c2 < 2; ++c2) {
                f32x4 acc = {0.0f, 0.0f, 0.0f, 0.0f};
                #pragma unroll
                for (int ks = 0; ks < 4; ++ks) {
                    acc = __builtin_amdgcn_mfma_f32_16x16x32_bf16(ah[ks], bh[c2][ks], acc, 0, 0, 0);
                    acc = __builtin_amdgcn_mfma_f32_16x16x32_bf16(al[ks], bh[c2][ks], acc, 0, 0, 0);
                    acc = __builtin_amdgcn_mfma_f32_16x16x32_bf16(ah[ks], bl[c2][ks], acc, 0, 0, 0);
                }
                #pragma unroll
                for (int v = 0; v < 4; ++v) {
                    const int row = jt * 16 + lg * 4 + v;   // j index
                    const float mv = silu_f(acc[v] + b2c[c2]);
                    const float add = (row == i) ? 0.0f : mv;
                    if (c2 == 0) msum0 += add; else msum1 += add;
                }
            }
        }
        msum0 += __shfl_xor(msum0, 16, 64); msum0 += __shfl_xor(msum0, 32, 64);
        msum1 += __shfl_xor(msum1, 16, 64); msum1 += __shfl_xor(msum1, 32, 64);
        if (lane < 16) {
            upd_l[il * 132 + 3 + (wv) * 16 + lr]     = msum0;
            upd_l[il * 132 + 3 + (wv + 4) * 16 + lr] = msum1;
        }
    }
    __syncthreads();       // A dead from here; reuse its space for u1_l

    float* u1_l = (float*)A_hi;   // 8*132*4 = 4224 B < 16 KB alias

    // ---- psi MLP: rep (tid>>7) handles 4 nodes; c = tid&127 (verbatim R11) ----
    const int c   = tid & 127;
    const int rep = tid >> 7;
    const int n0  = rep * 4;
    float a4[4];
    const float pb1 = psi_b1[c];
    #pragma unroll
    for (int nn = 0; nn < 4; ++nn) a4[nn] = pb1;
    #pragma unroll 4
    for (int k = 0; k < 131; ++k) {
        const float w = psi_w1[k * 128 + c];
        #pragma unroll
        for (int nn = 0; nn < 4; ++nn) a4[nn] += upd_l[(n0 + nn) * 132 + k] * w;
    }
    #pragma unroll
    for (int nn = 0; nn < 4; ++nn) u1_l[(n0 + nn) * 132 + c] = silu_f(a4[nn]);
    __syncthreads();

    const float pb2 = psi_b2[c];
    #pragma unroll
    for (int nn = 0; nn < 4; ++nn) a4[nn] = pb2;
    #pragma unroll 4
    for (int k = 0; k < 128; ++k) {
        const float w = psi_w2[k * 128 + c];
        #pragma unroll
        for (int nn = 0; nn < 4; ++nn) a4[nn] += u1_l[(n0 + nn) * 132 + k] * w;
    }
    float u2[4];
    #pragma unroll
    for (int nn = 0; nn < 4; ++nn) u2[nn] = silu_f(a4[nn]);

    const float w30 = psi_w3[c * 3 + 0];
    const float w31 = psi_w3[c * 3 + 1];
    const float w32 = psi_w3[c * 3 + 2];
    float pd[4][3];
    #pragma unroll
    for (int nn = 0; nn < 4; ++nn) {
        pd[nn][0] = u2[nn] * w30;
        pd[nn][1] = u2[nn] * w31;
        pd[nn][2] = u2[nn] * w32;
    }
    #pragma unroll
    for (int off = 32; off > 0; off >>= 1) {
        #pragma unroll
        for (int nn = 0; nn < 4; ++nn) {
            pd[nn][0] += __shfl_xor(pd[nn][0], off, 64);
            pd[nn][1] += __shfl_xor(pd[nn][1], off, 64);
            pd[nn][2] += __shfl_xor(pd[nn][2], off, 64);
        }
    }
    if (lane == 0) {
        #pragma unroll
        for (int nn = 0; nn < 4; ++nn) {
            red_l[wv * 12 + nn * 3 + 0] = pd[nn][0];
            red_l[wv * 12 + nn * 3 + 1] = pd[nn][1];
            red_l[wv * 12 + nn * 3 + 2] = pd[nn][2];
        }
    }
    __syncthreads();
    if (tid < 24) {
        const int n = tid / 3, d = tid % 3;
        const int wa = (n < 4) ? 0 : 2;
        const float dx = red_l[wa * 12 + (n & 3) * 3 + d]
                       + red_l[(wa + 1) * 12 + (n & 3) * 3 + d] + psi_b3[d];
        out[(b * 64 + i0 + n) * 3 + d] = tanhf(dx) * fmaxf(bf_scale[0], 0.0f);
    }
}

extern "C" void kernel_launch(void* const* d_in, const int* in_sizes, int n_in,
                              void* d_out, int out_size, void* d_ws, size_t ws_size,
                              hipStream_t stream) {
    const float* x        = (const float*)d_in[0];
    // d_in[1] = spin (unused: mask is all-ones off-diagonal)
    const float* phi_w1   = (const float*)d_in[2];
    const float* phi_b1   = (const float*)d_in[3];
    const float* phi_w2   = (const float*)d_in[4];
    const float* phi_b2   = (const float*)d_in[5];
    const float* psi_w1   = (const float*)d_in[6];
    const float* psi_b1   = (const float*)d_in[7];
    const float* psi_w2   = (const float*)d_in[8];
    const float* psi_b2   = (const float*)d_in[9];
    const float* psi_w3   = (const float*)d_in[10];
    const float* psi_b3   = (const float*)d_in[11];
    const float* bf_scale = (const float*)d_in[12];
    float* out = (float*)d_out;

    backflow_kernel<<<dim3(2048), dim3(NT), 0, stream>>>(
        x, phi_w1, phi_b1, phi_w2, phi_b2,
        psi_w1, psi_b1, psi_w2, psi_b2, psi_w3, psi_b3,
        bf_scale, out);
}